// Round 1
// baseline (2058.314 us; speedup 1.0000x reference)
//
#include <hip/hip_runtime.h>
#include <math.h>

#define B_ 4
#define H_ 64
#define W_ 64
#define L_ 4096
#define DM 96
#define DI 192
#define DS 16
#define RK 6
#define K_ 4
#define CPROJ 38   // RK + 2*DS
#define TL 8

__device__ __forceinline__ float sigmoidf_(float x){ return 1.0f/(1.0f+expf(-x)); }
__device__ __forceinline__ float softplusf_(float x){ return (x>20.f)?x:log1pf(expf(x)); }

// spatial index for scan direction k at scan position l (H=W=64)
__device__ __forceinline__ int spatial_idx(int k, int l){
  switch(k&3){
    case 0: return l;
    case 1: return ((l & 63) << 6) | (l >> 6);
    case 2: return L_-1-l;
    default: { int lp = L_-1-l; return ((lp & 63) << 6) | (lp >> 6); }
  }
}

// -------- K1: in_proj GEMM. xz = x @ W^T; split -> xin (B,DI,L), z (B,L,DI)
__global__ void k_inproj(const float* __restrict__ x, const float* __restrict__ w,
                         float* __restrict__ xin, float* __restrict__ z){
  __shared__ float xs[TL][DM];
  int t = threadIdx.x;                     // 0..383
  long bl0 = (long)blockIdx.x * TL;        // row index over B*L
  for (int i = t; i < TL*DM; i += 384)
    xs[i/DM][i%DM] = x[bl0*DM + i];
  __syncthreads();
  float acc[TL];
  #pragma unroll
  for (int r=0;r<TL;r++) acc[r]=0.f;
  const float* wr = w + t*DM;
  for (int c=0;c<DM;c++){
    float wv = wr[c];
    #pragma unroll
    for (int r=0;r<TL;r++) acc[r] += wv * xs[r][c];
  }
  int b  = (int)(bl0 / L_);
  int l0 = (int)(bl0 % L_);
  if (t < DI){
    for (int r=0;r<TL;r++)
      xin[((long)b*DI + t)*L_ + l0 + r] = acc[r];
  } else {
    int e = t - DI;
    for (int r=0;r<TL;r++)
      z[((long)b*L_ + l0 + r)*DI + e] = acc[r];
  }
}

// -------- K2: depthwise conv 3x3 (pad 1) + bias + SiLU -> xc (B,DI,L)
__global__ void k_conv(const float* __restrict__ xin, const float* __restrict__ cw,
                       const float* __restrict__ cb, float* __restrict__ xc){
  long idx = (long)blockIdx.x*256 + threadIdx.x;
  if (idx >= (long)B_*DI*L_) return;
  int l = (int)(idx % L_); long bd = idx / L_;
  int d = (int)(bd % DI);
  int h = l >> 6, w = l & 63;
  const float* wp = cw + d*9;
  const float* xp = xin + bd*L_;
  float acc = cb[d];
  #pragma unroll
  for (int di=0; di<3; di++){
    int hh = h + di - 1;
    if (hh < 0 || hh >= H_) continue;
    #pragma unroll
    for (int dj=0; dj<3; dj++){
      int ww = w + dj - 1;
      if (ww < 0 || ww >= W_) continue;
      acc += xp[(hh<<6) + ww] * wp[di*3+dj];
    }
  }
  xc[idx] = acc * sigmoidf_(acc);
}

// -------- K3: x_proj (38x192) + dt_proj (192x6) + softplus per (b,k,l-tile)
__global__ void k_proj(const float* __restrict__ xc, const float* __restrict__ xpw,
                       const float* __restrict__ dtw, const float* __restrict__ dtb,
                       float* __restrict__ delta, float* __restrict__ Bsb, float* __restrict__ Csb){
  __shared__ float xt[DI][64];     // 49152 B
  __shared__ float proj[CPROJ][64];// 9728 B
  int t = threadIdx.x;
  int blk = blockIdx.x;            // b*K*64 + k*64 + lt
  int lt = blk & 63;
  int k  = (blk >> 6) & 3;
  int b  = blk >> 8;
  int l0 = lt * 64;
  const float* xcb = xc + (long)b*DI*L_;
  for (int i = t; i < DI*64; i += 256){
    int d = i >> 6, li = i & 63;
    xt[d][li] = xcb[(long)d*L_ + spatial_idx(k, l0+li)];
  }
  __syncthreads();
  for (int i = t; i < CPROJ*64; i += 256){
    int c = i >> 6, li = i & 63;
    const float* wrow = xpw + (long)(k*CPROJ + c)*DI;
    float acc = 0.f;
    for (int d=0; d<DI; d++) acc += xt[d][li]*wrow[d];
    proj[c][li] = acc;
  }
  __syncthreads();
  for (int i = t; i < 2*DS*64; i += 256){
    int c = i >> 6, li = i & 63;
    float v = proj[RK + c][li];
    if (c < DS) Bsb[(((long)b*K_ + k)*DS + c)      *L_ + l0 + li] = v;
    else        Csb[(((long)b*K_ + k)*DS + (c-DS))*L_ + l0 + li] = v;
  }
  for (int i = t; i < DI*64; i += 256){
    int d = i >> 6, li = i & 63;
    const float* wr = dtw + (long)(k*DI + d)*RK;
    float acc = dtb[k*DI + d];
    #pragma unroll
    for (int r=0; r<RK; r++) acc += proj[r][li]*wr[r];
    delta[(((long)b*K_ + k)*DI + d)*L_ + l0 + li] = softplusf_(acc);
  }
}

// -------- K4: selective scan. thread = (b,k,d,n). ys layout (B,K,L,DI)
__global__ void k_scan(const float* __restrict__ xc, const float* __restrict__ delta,
                       const float* __restrict__ Bsb, const float* __restrict__ Csb,
                       const float* __restrict__ Alog, const float* __restrict__ Dvec,
                       float* __restrict__ ys){
  int t = threadIdx.x;
  int n  = t & 15;
  int dl = t >> 4;               // 0..15
  int blk = blockIdx.x;          // (b*K + k)*12 + dblk
  int dblk = blk % 12;
  int bk = blk / 12;
  int k = bk & 3;
  int b = bk >> 2;
  int d = dblk*16 + dl;
  float An = -expf(Alog[(k*DI + d)*DS + n]);
  float Dv = Dvec[k*DI + d];
  const float* dp = delta + ((long)bk*DI + d)*L_;
  const float* Bp = Bsb + ((long)bk*DS + n)*L_;
  const float* Cp = Csb + ((long)bk*DS + n)*L_;
  const float* xp = xc + ((long)b*DI + d)*L_;
  float* yp = ys + (long)bk*L_*DI + d;
  float h = 0.f;
  for (int l=0; l<L_; l++){
    float dt = dp[l];
    float u  = xp[spatial_idx(k,l)];
    float bv = Bp[l], cv = Cp[l];
    h = expf(dt*An)*h + (dt*u)*bv;
    float y = h*cv;
    y += __shfl_xor(y,1); y += __shfl_xor(y,2); y += __shfl_xor(y,4); y += __shfl_xor(y,8);
    if (n==0) yp[(long)l*DI] = y + Dv*u;
  }
}

// -------- K5: merge directions + LayerNorm + SiLU(z) gate + out_proj
__global__ void k_out(const float* __restrict__ ys, const float* __restrict__ z,
                      const float* __restrict__ lng, const float* __restrict__ lnb,
                      const float* __restrict__ opw, float* __restrict__ out){
  __shared__ float red[6];
  __shared__ float yl[DI];
  int d  = threadIdx.x;          // 0..191
  int bi = blockIdx.x;           // b*L + s
  int b = bi >> 12;
  int s = bi & 4095;
  int h = s >> 6, w = s & 63;
  int pos1 = (w<<6) | h;
  long base = (long)b*K_*L_*DI;
  float y = ys[base + ((long)0*L_ + s)          *DI + d]
          + ys[base + ((long)1*L_ + pos1)       *DI + d]
          + ys[base + ((long)2*L_ + (L_-1-s))   *DI + d]
          + ys[base + ((long)3*L_ + (L_-1-pos1))*DI + d];
  float s1 = y, s2 = y*y;
  int lane = d & 63, wid = d >> 6;
  for (int off=32; off; off>>=1){
    s1 += __shfl_down(s1,off);
    s2 += __shfl_down(s2,off);
  }
  if (lane==0){ red[wid]=s1; red[3+wid]=s2; }
  __syncthreads();
  float sum = red[0]+red[1]+red[2];
  float sq  = red[3]+red[4]+red[5];
  float mu  = sum * (1.f/DI);
  float var = sq*(1.f/DI) - mu*mu;
  float yn = (y-mu)*rsqrtf(var+1e-5f)*lng[d] + lnb[d];
  float zv = z[((long)b*L_ + s)*DI + d];
  float yg = yn * (zv * sigmoidf_(zv));
  yl[d] = yg;
  __syncthreads();
  if (d < DM){
    const float* wr = opw + (long)d*DI;
    float acc = 0.f;
    for (int dd=0; dd<DI; dd++) acc += yl[dd]*wr[dd];
    out[((long)b*L_ + s)*DM + d] = acc;
  }
}

extern "C" void kernel_launch(void* const* d_in, const int* in_sizes, int n_in,
                              void* d_out, int out_size, void* d_ws, size_t ws_size,
                              hipStream_t stream){
  const float* x    = (const float*)d_in[0];
  const float* ipw  = (const float*)d_in[1];
  const float* cw   = (const float*)d_in[2];
  const float* cb   = (const float*)d_in[3];
  const float* xpw  = (const float*)d_in[4];
  const float* dtw  = (const float*)d_in[5];
  const float* dtb  = (const float*)d_in[6];
  const float* Alog = (const float*)d_in[7];
  const float* Dvec = (const float*)d_in[8];
  const float* lng  = (const float*)d_in[9];
  const float* lnb  = (const float*)d_in[10];
  const float* opw  = (const float*)d_in[11];
  float* out = (float*)d_out;

  float* ws = (float*)d_ws;
  long szBDL = (long)B_*DI*L_;          // 3,145,728
  long szBKDL = (long)B_*K_*DI*L_;      // 12,582,912
  long szBKNL = (long)B_*K_*DS*L_;      // 1,048,576
  float* xin   = ws;
  float* z     = xin + szBDL;
  float* xc    = z + szBDL;
  float* delta = xc + szBDL;
  float* Bsb   = delta + szBKDL;
  float* Csb   = Bsb + szBKNL;
  float* ysb   = Csb + szBKNL;

  hipLaunchKernelGGL(k_inproj, dim3(B_*L_/TL), dim3(384), 0, stream, x, ipw, xin, z);
  hipLaunchKernelGGL(k_conv, dim3((int)((szBDL)/256)), dim3(256), 0, stream, xin, cw, cb, xc);
  hipLaunchKernelGGL(k_proj, dim3(B_*K_*64), dim3(256), 0, stream, xc, xpw, dtw, dtb, delta, Bsb, Csb);
  hipLaunchKernelGGL(k_scan, dim3(B_*K_*12), dim3(256), 0, stream, xc, delta, Bsb, Csb, Alog, Dvec, ysb);
  hipLaunchKernelGGL(k_out, dim3(B_*L_), dim3(192), 0, stream, ysb, z, lng, lnb, opw, out);
}

// Round 2
// 777.738 us; speedup vs baseline: 2.6465x; 2.6465x over previous
//
#include <hip/hip_runtime.h>
#include <math.h>

#define B_ 4
#define H_ 64
#define W_ 64
#define L_ 4096
#define DM 96
#define DI 192
#define DS 16
#define RK 6
#define K_ 4
#define CPROJ 38   // RK + 2*DS
#define TL 8
#define NC 64      // chunks for two-pass scan
#define CL 64      // chunk length (NC*CL = L_)

__device__ __forceinline__ float sigmoidf_(float x){ return 1.0f/(1.0f+expf(-x)); }
__device__ __forceinline__ float softplusf_(float x){ return (x>20.f)?x:log1pf(expf(x)); }

// spatial index for scan direction k at scan position l (H=W=64)
__device__ __forceinline__ int spatial_idx(int k, int l){
  switch(k&3){
    case 0: return l;
    case 1: return ((l & 63) << 6) | (l >> 6);
    case 2: return L_-1-l;
    default: { int lp = L_-1-l; return ((lp & 63) << 6) | (lp >> 6); }
  }
}

// -------- K1: in_proj GEMM. xz = x @ W^T; split -> xin (B,DI,L), z (B,L,DI)
__global__ void k_inproj(const float* __restrict__ x, const float* __restrict__ w,
                         float* __restrict__ xin, float* __restrict__ z){
  __shared__ float xs[TL][DM];
  int t = threadIdx.x;                     // 0..383
  long bl0 = (long)blockIdx.x * TL;        // row index over B*L
  for (int i = t; i < TL*DM; i += 384)
    xs[i/DM][i%DM] = x[bl0*DM + i];
  __syncthreads();
  float acc[TL];
  #pragma unroll
  for (int r=0;r<TL;r++) acc[r]=0.f;
  const float* wr = w + t*DM;
  for (int c=0;c<DM;c++){
    float wv = wr[c];
    #pragma unroll
    for (int r=0;r<TL;r++) acc[r] += wv * xs[r][c];
  }
  int b  = (int)(bl0 / L_);
  int l0 = (int)(bl0 % L_);
  if (t < DI){
    for (int r=0;r<TL;r++)
      xin[((long)b*DI + t)*L_ + l0 + r] = acc[r];
  } else {
    int e = t - DI;
    for (int r=0;r<TL;r++)
      z[((long)b*L_ + l0 + r)*DI + e] = acc[r];
  }
}

// -------- K2: depthwise conv 3x3 (pad 1) + bias + SiLU -> xc (B,DI,L)
__global__ void k_conv(const float* __restrict__ xin, const float* __restrict__ cw,
                       const float* __restrict__ cb, float* __restrict__ xc){
  long idx = (long)blockIdx.x*256 + threadIdx.x;
  if (idx >= (long)B_*DI*L_) return;
  int l = (int)(idx % L_); long bd = idx / L_;
  int d = (int)(bd % DI);
  int h = l >> 6, w = l & 63;
  const float* wp = cw + d*9;
  const float* xp = xin + bd*L_;
  float acc = cb[d];
  #pragma unroll
  for (int di=0; di<3; di++){
    int hh = h + di - 1;
    if (hh < 0 || hh >= H_) continue;
    #pragma unroll
    for (int dj=0; dj<3; dj++){
      int ww = w + dj - 1;
      if (ww < 0 || ww >= W_) continue;
      acc += xp[(hh<<6) + ww] * wp[di*3+dj];
    }
  }
  xc[idx] = acc * sigmoidf_(acc);
}

// -------- K3: x_proj (38x192) + dt_proj (192x6) + softplus per (b,k,l-tile)
__global__ void k_proj(const float* __restrict__ xc, const float* __restrict__ xpw,
                       const float* __restrict__ dtw, const float* __restrict__ dtb,
                       float* __restrict__ delta, float* __restrict__ Bsb, float* __restrict__ Csb){
  __shared__ float xt[DI][64];     // 49152 B
  __shared__ float proj[CPROJ][64];// 9728 B
  int t = threadIdx.x;
  int blk = blockIdx.x;            // b*K*64 + k*64 + lt
  int lt = blk & 63;
  int k  = (blk >> 6) & 3;
  int b  = blk >> 8;
  int l0 = lt * 64;
  const float* xcb = xc + (long)b*DI*L_;
  for (int i = t; i < DI*64; i += 256){
    int d = i >> 6, li = i & 63;
    xt[d][li] = xcb[(long)d*L_ + spatial_idx(k, l0+li)];
  }
  __syncthreads();
  for (int i = t; i < CPROJ*64; i += 256){
    int c = i >> 6, li = i & 63;
    const float* wrow = xpw + (long)(k*CPROJ + c)*DI;
    float acc = 0.f;
    for (int d=0; d<DI; d++) acc += xt[d][li]*wrow[d];
    proj[c][li] = acc;
  }
  __syncthreads();
  for (int i = t; i < 2*DS*64; i += 256){
    int c = i >> 6, li = i & 63;
    float v = proj[RK + c][li];
    if (c < DS) Bsb[(((long)b*K_ + k)*DS + c)      *L_ + l0 + li] = v;
    else        Csb[(((long)b*K_ + k)*DS + (c-DS))*L_ + l0 + li] = v;
  }
  for (int i = t; i < DI*64; i += 256){
    int d = i >> 6, li = i & 63;
    const float* wr = dtw + (long)(k*DI + d)*RK;
    float acc = dtb[k*DI + d];
    #pragma unroll
    for (int r=0; r<RK; r++) acc += proj[r][li]*wr[r];
    delta[(((long)b*K_ + k)*DI + d)*L_ + l0 + li] = softplusf_(acc);
  }
}

// -------- K4a: chunked scan pass A — local scan per chunk, h0=0.
// block = ((bk*12 + dblk)<<6) | chunk ; thread = dl*16 + n
// outputs: aprod/hend at [((bk*NC+chunk)*12+dblk)*256 + t]
__global__ void k_scanA(const float* __restrict__ xc, const float* __restrict__ delta,
                        const float* __restrict__ Bsb, const float* __restrict__ Alog,
                        float* __restrict__ aprod, float* __restrict__ hend){
  int t = threadIdx.x;
  int n  = t & 15;
  int dl = t >> 4;
  int blk = blockIdx.x;
  int chunk = blk & (NC-1);
  int rest = blk >> 6;             // bk*12 + dblk
  int dblk = rest % 12;
  int bk = rest / 12;
  int k = bk & 3, b = bk >> 2;
  int d = dblk*16 + dl;
  float An2 = -expf(Alog[(k*DI + d)*DS + n]) * 1.44269504f;
  int l0 = chunk * CL;
  const float* dp = delta + ((long)bk*DI + d)*L_ + l0;
  const float* Bp = Bsb + ((long)bk*DS + n)*L_ + l0;
  const float* xp = xc + ((long)b*DI + d)*L_;
  float ap = 1.f, h = 0.f;
  for (int l4 = 0; l4 < CL; l4 += 4){
    float4 d4 = *(const float4*)(dp + l4);
    float4 b4 = *(const float4*)(Bp + l4);
    #pragma unroll
    for (int j = 0; j < 4; j++){
      float dt = j==0?d4.x:j==1?d4.y:j==2?d4.z:d4.w;
      float bv = j==0?b4.x:j==1?b4.y:j==2?b4.z:b4.w;
      float u  = xp[spatial_idx(k, l0 + l4 + j)];
      float a  = exp2f(dt * An2);
      ap *= a;
      h = a*h + (dt*u)*bv;
    }
  }
  long idx = ((long)(bk*NC + chunk)*12 + dblk)*256 + t;
  aprod[idx] = ap;
  hend[idx]  = h;
}

// -------- K4b: scan over chunks. block = bk*12+dblk, thread = dl*16+n.
// reads aprod/hend; writes hstart IN-PLACE into aprod.
__global__ void k_scanB(float* __restrict__ aprod, float* __restrict__ hend){
  int t = threadIdx.x;
  int rest = blockIdx.x;           // bk*12 + dblk
  int dblk = rest % 12;
  int bk = rest / 12;
  float hs = 0.f;
  for (int c = 0; c < NC; c++){
    long idx = ((long)(bk*NC + c)*12 + dblk)*256 + t;
    float ap = aprod[idx];
    float he = hend[idx];
    aprod[idx] = hs;               // hstart for chunk c
    hs = ap*hs + he;
  }
}

// -------- K4c: pass C — recompute local scan seeded with hstart, emit y.
__global__ void k_scanC(const float* __restrict__ xc, const float* __restrict__ delta,
                        const float* __restrict__ Bsb, const float* __restrict__ Csb,
                        const float* __restrict__ Alog, const float* __restrict__ Dvec,
                        const float* __restrict__ hstart, float* __restrict__ ys){
  int t = threadIdx.x;
  int n  = t & 15;
  int dl = t >> 4;
  int blk = blockIdx.x;
  int chunk = blk & (NC-1);
  int rest = blk >> 6;
  int dblk = rest % 12;
  int bk = rest / 12;
  int k = bk & 3, b = bk >> 2;
  int d = dblk*16 + dl;
  float An2 = -expf(Alog[(k*DI + d)*DS + n]) * 1.44269504f;
  float Dv = Dvec[k*DI + d];
  int l0 = chunk * CL;
  const float* dp = delta + ((long)bk*DI + d)*L_ + l0;
  const float* Bp = Bsb + ((long)bk*DS + n)*L_ + l0;
  const float* Cp = Csb + ((long)bk*DS + n)*L_ + l0;
  const float* xp = xc + ((long)b*DI + d)*L_;
  float* yp = ys + (long)bk*L_*DI + (long)l0*DI + d;
  float h = hstart[((long)(bk*NC + chunk)*12 + dblk)*256 + t];
  for (int l4 = 0; l4 < CL; l4 += 4){
    float4 d4 = *(const float4*)(dp + l4);
    float4 b4 = *(const float4*)(Bp + l4);
    float4 c4 = *(const float4*)(Cp + l4);
    #pragma unroll
    for (int j = 0; j < 4; j++){
      float dt = j==0?d4.x:j==1?d4.y:j==2?d4.z:d4.w;
      float bv = j==0?b4.x:j==1?b4.y:j==2?b4.z:b4.w;
      float cv = j==0?c4.x:j==1?c4.y:j==2?c4.z:c4.w;
      float u  = xp[spatial_idx(k, l0 + l4 + j)];
      float a  = exp2f(dt * An2);
      h = a*h + (dt*u)*bv;
      float y = h*cv;
      y += __shfl_xor(y,1); y += __shfl_xor(y,2); y += __shfl_xor(y,4); y += __shfl_xor(y,8);
      if (n == 0) yp[(long)(l4+j)*DI] = y + Dv*u;
    }
  }
}

// -------- K5: merge directions + LayerNorm + SiLU(z) gate + out_proj
__global__ void k_out(const float* __restrict__ ys, const float* __restrict__ z,
                      const float* __restrict__ lng, const float* __restrict__ lnb,
                      const float* __restrict__ opw, float* __restrict__ out){
  __shared__ float red[6];
  __shared__ float yl[DI];
  int d  = threadIdx.x;          // 0..191
  int bi = blockIdx.x;           // b*L + s
  int b = bi >> 12;
  int s = bi & 4095;
  int h = s >> 6, w = s & 63;
  int pos1 = (w<<6) | h;
  long base = (long)b*K_*L_*DI;
  float y = ys[base + ((long)0*L_ + s)          *DI + d]
          + ys[base + ((long)1*L_ + pos1)       *DI + d]
          + ys[base + ((long)2*L_ + (L_-1-s))   *DI + d]
          + ys[base + ((long)3*L_ + (L_-1-pos1))*DI + d];
  float s1 = y, s2 = y*y;
  int lane = d & 63, wid = d >> 6;
  for (int off=32; off; off>>=1){
    s1 += __shfl_down(s1,off);
    s2 += __shfl_down(s2,off);
  }
  if (lane==0){ red[wid]=s1; red[3+wid]=s2; }
  __syncthreads();
  float sum = red[0]+red[1]+red[2];
  float sq  = red[3]+red[4]+red[5];
  float mu  = sum * (1.f/DI);
  float var = sq*(1.f/DI) - mu*mu;
  float yn = (y-mu)*rsqrtf(var+1e-5f)*lng[d] + lnb[d];
  float zv = z[((long)b*L_ + s)*DI + d];
  float yg = yn * (zv * sigmoidf_(zv));
  yl[d] = yg;
  __syncthreads();
  if (d < DM){
    const float* wr = opw + (long)d*DI;
    float acc = 0.f;
    for (int dd=0; dd<DI; dd++) acc += yl[dd]*wr[dd];
    out[((long)b*L_ + s)*DM + d] = acc;
  }
}

extern "C" void kernel_launch(void* const* d_in, const int* in_sizes, int n_in,
                              void* d_out, int out_size, void* d_ws, size_t ws_size,
                              hipStream_t stream){
  const float* x    = (const float*)d_in[0];
  const float* ipw  = (const float*)d_in[1];
  const float* cw   = (const float*)d_in[2];
  const float* cb   = (const float*)d_in[3];
  const float* xpw  = (const float*)d_in[4];
  const float* dtw  = (const float*)d_in[5];
  const float* dtb  = (const float*)d_in[6];
  const float* Alog = (const float*)d_in[7];
  const float* Dvec = (const float*)d_in[8];
  const float* lng  = (const float*)d_in[9];
  const float* lnb  = (const float*)d_in[10];
  const float* opw  = (const float*)d_in[11];
  float* out = (float*)d_out;

  float* ws = (float*)d_ws;
  long szBDL = (long)B_*DI*L_;          // 3,145,728
  long szBKDL = (long)B_*K_*DI*L_;      // 12,582,912
  long szBKNL = (long)B_*K_*DS*L_;      // 1,048,576
  float* xin   = ws;                    // dead after k_conv -> reused as aprod/hstart
  float* z     = xin + szBDL;
  float* xc    = z + szBDL;
  float* delta = xc + szBDL;
  float* Bsb   = delta + szBKDL;
  float* Csb   = Bsb + szBKNL;
  float* ysb   = Csb + szBKNL;
  // overlays (no extra footprint):
  float* aprod = xin;                   // B*K*NC*12*256 = 3,145,728 floats (exact fit)
  float* hend  = ysb;                   // head of ys; dead before pass C writes ys

  hipLaunchKernelGGL(k_inproj, dim3(B_*L_/TL), dim3(384), 0, stream, x, ipw, xin, z);
  hipLaunchKernelGGL(k_conv, dim3((int)((szBDL)/256)), dim3(256), 0, stream, xin, cw, cb, xc);
  hipLaunchKernelGGL(k_proj, dim3(B_*K_*64), dim3(256), 0, stream, xc, xpw, dtw, dtb, delta, Bsb, Csb);
  hipLaunchKernelGGL(k_scanA, dim3(B_*K_*12*NC), dim3(256), 0, stream, xc, delta, Bsb, Alog, aprod, hend);
  hipLaunchKernelGGL(k_scanB, dim3(B_*K_*12), dim3(256), 0, stream, aprod, hend);
  hipLaunchKernelGGL(k_scanC, dim3(B_*K_*12*NC), dim3(256), 0, stream, xc, delta, Bsb, Csb, Alog, Dvec, aprod, ysb);
  hipLaunchKernelGGL(k_out, dim3(B_*L_), dim3(192), 0, stream, ysb, z, lng, lnb, opw, out);
}

// Round 3
// 605.531 us; speedup vs baseline: 3.3992x; 1.2844x over previous
//
#include <hip/hip_runtime.h>
#include <math.h>

#define B_ 4
#define H_ 64
#define W_ 64
#define L_ 4096
#define DM 96
#define DI 192
#define DS 16
#define RK 6
#define K_ 4
#define CPROJ 38   // RK + 2*DS
#define TL 8
#define NC 64      // chunks
#define CL 64      // chunk length

__device__ __forceinline__ float sigmoidf_(float x){ return 1.0f/(1.0f+expf(-x)); }
__device__ __forceinline__ float softplusf_(float x){ return (x>20.f)?x:log1pf(expf(x)); }

// spatial index for scan direction k at scan position l (H=W=64)
__device__ __forceinline__ int spatial_idx(int k, int l){
  switch(k&3){
    case 0: return l;
    case 1: return ((l & 63) << 6) | (l >> 6);
    case 2: return L_-1-l;
    default: { int lp = L_-1-l; return ((lp & 63) << 6) | (lp >> 6); }
  }
}

// -------- K1: in_proj GEMM. xin (B,L,DI), z (B,L,DI)
__global__ void k_inproj(const float* __restrict__ x, const float* __restrict__ w,
                         float* __restrict__ xin, float* __restrict__ z){
  __shared__ float xs[TL][DM];
  int t = threadIdx.x;                     // 0..383
  long bl0 = (long)blockIdx.x * TL;
  for (int i = t; i < TL*DM; i += 384)
    xs[i/DM][i%DM] = x[bl0*DM + i];
  __syncthreads();
  float acc[TL];
  #pragma unroll
  for (int r=0;r<TL;r++) acc[r]=0.f;
  const float* wr = w + t*DM;
  for (int c=0;c<DM;c++){
    float wv = wr[c];
    #pragma unroll
    for (int r=0;r<TL;r++) acc[r] += wv * xs[r][c];
  }
  if (t < DI){
    for (int r=0;r<TL;r++)
      xin[(bl0 + r)*DI + t] = acc[r];
  } else {
    int e = t - DI;
    for (int r=0;r<TL;r++)
      z[(bl0 + r)*DI + e] = acc[r];
  }
}

// -------- K2: depthwise conv 3x3 + bias + SiLU. (B,L,DI) -> (B,L,DI)
__global__ void k_conv(const float* __restrict__ xin, const float* __restrict__ cw,
                       const float* __restrict__ cb, float* __restrict__ xc){
  long idx = (long)blockIdx.x*256 + threadIdx.x;
  if (idx >= (long)B_*L_*DI) return;
  int d = (int)(idx % DI);
  long bl = idx / DI;
  int l = (int)(bl % L_);
  long b = bl / L_;
  int h = l >> 6, w = l & 63;
  const float* wp = cw + d*9;
  const float* xp = xin + b*L_*DI + d;
  float acc = cb[d];
  #pragma unroll
  for (int di=0; di<3; di++){
    int hh = h + di - 1;
    if (hh < 0 || hh >= H_) continue;
    #pragma unroll
    for (int dj=0; dj<3; dj++){
      int ww = w + dj - 1;
      if (ww < 0 || ww >= W_) continue;
      acc += xp[(long)((hh<<6) + ww)*DI] * wp[di*3+dj];
    }
  }
  xc[idx] = acc * sigmoidf_(acc);
}

// -------- K3: x_proj + dt_proj + softplus. delta (BK,L,DI), Bs/Cs (BK,L,DS)
__global__ void k_proj(const float* __restrict__ xc, const float* __restrict__ xpw,
                       const float* __restrict__ dtw, const float* __restrict__ dtb,
                       float* __restrict__ delta, float* __restrict__ Bsb, float* __restrict__ Csb){
  __shared__ float xt[64][DI+1];    // [li][d], pad -> conflict-free column reads
  __shared__ float proj[CPROJ][65]; // [c][li], pad
  int t = threadIdx.x;              // 0..255
  int blk = blockIdx.x;             // b*K*64 + k*64 + lt
  int lt = blk & 63;
  int k  = (blk >> 6) & 3;
  int b  = blk >> 8;
  int l0 = lt * 64;
  int bk = b*K_ + k;
  const float* xcb = xc + (long)b*L_*DI;
  for (int i = t; i < 64*DI; i += 256){
    int d = i % DI, li = i / DI;
    xt[li][d] = xcb[(long)spatial_idx(k, l0+li)*DI + d];
  }
  __syncthreads();
  // x_proj: wave wv handles c = wv, wv+4, ... (wave-uniform rows -> s_load)
  {
    int wv = __builtin_amdgcn_readfirstlane(t >> 6); // wave id 0..3
    int li = t & 63;
    float acc[10];
    #pragma unroll
    for (int j=0;j<10;j++) acc[j]=0.f;
    const float* wbase = xpw + (long)k*CPROJ*DI;
    for (int dd=0; dd<DI; dd++){
      float xv = xt[li][dd];
      #pragma unroll
      for (int j=0;j<10;j++){
        int c = wv + 4*j;
        if (c < CPROJ) acc[j] += xv * wbase[c*DI + dd];
      }
    }
    #pragma unroll
    for (int j=0;j<10;j++){
      int c = wv + 4*j;
      if (c < CPROJ) proj[c][li] = acc[j];
    }
  }
  __syncthreads();
  // B/C split, layout (bk, l, n)
  for (int i = t; i < 64*2*DS; i += 256){
    int li = i >> 5, c = i & 31;
    float v = proj[RK + c][li];
    if (c < DS) Bsb[((long)bk*L_ + l0 + li)*DS + c]        = v;
    else        Csb[((long)bk*L_ + l0 + li)*DS + (c-DS)]   = v;
  }
  // dt_proj + softplus, layout (bk, l, d)
  for (int i = t; i < 64*DI; i += 256){
    int d = i % DI, li = i / DI;
    const float* wr = dtw + (long)(k*DI + d)*RK;
    float acc = dtb[k*DI + d];
    #pragma unroll
    for (int r=0; r<RK; r++) acc += proj[r][li]*wr[r];
    delta[((long)bk*L_ + l0 + li)*DI + d] = softplusf_(acc);
  }
}

__device__ __forceinline__ void scan_addr(int k, int chunk, int l0, int& sbase, int& sstep){
  switch(k){
    case 0: sbase = l0;            sstep = 1;   break;
    case 1: sbase = chunk;         sstep = 64;  break;
    case 2: sbase = L_-1-l0;       sstep = -1;  break;
    default: sbase = 4032 + 63 - chunk; sstep = -64; break;
  }
}

// -------- K4a: pass A. block=(bk,chunk), thread=d holds 16 n-states.
__global__ void k_scanA(const float* __restrict__ xc, const float* __restrict__ delta,
                        const float* __restrict__ Bsb, const float* __restrict__ Alog,
                        float* __restrict__ aprod, float* __restrict__ hend){
  __shared__ float Bt[CL][DS];
  int d = threadIdx.x;             // 0..191
  int blk = blockIdx.x;            // bk*NC + chunk
  int chunk = blk & (NC-1);
  int bk = blk >> 6;
  int k = bk & 3, b = bk >> 2;
  int l0 = chunk * CL;
  const float* Bg = Bsb + ((long)bk*L_ + l0)*DS;
  for (int i = d; i < CL*DS; i += 192) ((float*)Bt)[i] = Bg[i];
  float An2[DS], h[DS], ap[DS];
  const float* Ap = Alog + (k*DI + d)*DS;
  #pragma unroll
  for (int n=0;n<DS;n++){ An2[n] = -expf(Ap[n])*1.44269504f; h[n]=0.f; ap[n]=1.f; }
  __syncthreads();
  int sbase, sstep; scan_addr(k, chunk, l0, sbase, sstep);
  const float* dp = delta + ((long)bk*L_ + l0)*DI + d;
  const float* xp = xc + (long)b*L_*DI + d;
  for (int l=0; l<CL; l++){
    float dt = dp[(long)l*DI];
    float u  = xp[(long)(sbase + l*sstep)*DI];
    float dtu = dt*u;
    float bvf[DS];
    *(float4*)(bvf+0)  = *(const float4*)&Bt[l][0];
    *(float4*)(bvf+4)  = *(const float4*)&Bt[l][4];
    *(float4*)(bvf+8)  = *(const float4*)&Bt[l][8];
    *(float4*)(bvf+12) = *(const float4*)&Bt[l][12];
    #pragma unroll
    for (int n=0;n<DS;n++){
      float a = exp2f(dt*An2[n]);
      ap[n] *= a;
      h[n] = a*h[n] + dtu*bvf[n];
    }
  }
  long ob = ((long)blk*DI + d)*DS;
  #pragma unroll
  for (int q=0;q<4;q++){
    *(float4*)(aprod + ob + q*4) = make_float4(ap[q*4],ap[q*4+1],ap[q*4+2],ap[q*4+3]);
    *(float4*)(hend  + ob + q*4) = make_float4(h[q*4], h[q*4+1], h[q*4+2], h[q*4+3]);
  }
}

// -------- K4b: chunk-scan, register-batched. hstart written in-place to aprod.
__global__ void k_scanB(float* __restrict__ aprod, float* __restrict__ hend){
  int t = threadIdx.x;             // (dl,n) = 256
  int blk = blockIdx.x;            // bk*12 + p
  int p = blk % 12;
  int bk = blk / 12;
  long base = (long)bk*NC*DI*DS + p*256 + t;
  const long cstride = (long)DI*DS;   // 3072
  float hs = 0.f;
  for (int cb = 0; cb < NC; cb += 16){
    float a[16], e[16];
    #pragma unroll
    for (int j=0;j<16;j++){
      long idx = base + (long)(cb+j)*cstride;
      a[j] = aprod[idx];
      e[j] = hend[idx];
    }
    #pragma unroll
    for (int j=0;j<16;j++){
      long idx = base + (long)(cb+j)*cstride;
      aprod[idx] = hs;             // hstart for chunk cb+j
      hs = a[j]*hs + e[j];
    }
  }
}

// -------- K4c: pass C. seeded local scan, y = <h,C> + D*u. ys (BK,L,DI)
__global__ void k_scanC(const float* __restrict__ xc, const float* __restrict__ delta,
                        const float* __restrict__ Bsb, const float* __restrict__ Csb,
                        const float* __restrict__ Alog, const float* __restrict__ Dvec,
                        const float* __restrict__ hstart, float* __restrict__ ys){
  __shared__ float Bt[CL][DS];
  __shared__ float Ct[CL][DS];
  int d = threadIdx.x;
  int blk = blockIdx.x;
  int chunk = blk & (NC-1);
  int bk = blk >> 6;
  int k = bk & 3, b = bk >> 2;
  int l0 = chunk * CL;
  const float* Bg = Bsb + ((long)bk*L_ + l0)*DS;
  const float* Cg = Csb + ((long)bk*L_ + l0)*DS;
  for (int i = d; i < CL*DS; i += 192){ ((float*)Bt)[i] = Bg[i]; ((float*)Ct)[i] = Cg[i]; }
  float An2[DS], h[DS];
  const float* Ap = Alog + (k*DI + d)*DS;
  #pragma unroll
  for (int n=0;n<DS;n++) An2[n] = -expf(Ap[n])*1.44269504f;
  long hb = ((long)blk*DI + d)*DS;
  #pragma unroll
  for (int q=0;q<4;q++){
    float4 hv = *(const float4*)(hstart + hb + q*4);
    h[q*4]=hv.x; h[q*4+1]=hv.y; h[q*4+2]=hv.z; h[q*4+3]=hv.w;
  }
  float Dv = Dvec[k*DI + d];
  __syncthreads();
  int sbase, sstep; scan_addr(k, chunk, l0, sbase, sstep);
  const float* dp = delta + ((long)bk*L_ + l0)*DI + d;
  const float* xp = xc + (long)b*L_*DI + d;
  float* yp = ys + ((long)bk*L_ + l0)*DI + d;
  for (int l=0; l<CL; l++){
    float dt = dp[(long)l*DI];
    float u  = xp[(long)(sbase + l*sstep)*DI];
    float dtu = dt*u;
    float bvf[DS], cvf[DS];
    *(float4*)(bvf+0)  = *(const float4*)&Bt[l][0];
    *(float4*)(bvf+4)  = *(const float4*)&Bt[l][4];
    *(float4*)(bvf+8)  = *(const float4*)&Bt[l][8];
    *(float4*)(bvf+12) = *(const float4*)&Bt[l][12];
    *(float4*)(cvf+0)  = *(const float4*)&Ct[l][0];
    *(float4*)(cvf+4)  = *(const float4*)&Ct[l][4];
    *(float4*)(cvf+8)  = *(const float4*)&Ct[l][8];
    *(float4*)(cvf+12) = *(const float4*)&Ct[l][12];
    float y = 0.f;
    #pragma unroll
    for (int n=0;n<DS;n++){
      float a = exp2f(dt*An2[n]);
      h[n] = a*h[n] + dtu*bvf[n];
      y += h[n]*cvf[n];
    }
    yp[(long)l*DI] = y + Dv*u;
  }
}

// -------- transpose out_proj weight: opwT[dd][o] = opw[o][dd]
__global__ void k_transpose(const float* __restrict__ opw, float* __restrict__ opwT){
  int idx = blockIdx.x*256 + threadIdx.x;
  if (idx >= DM*DI) return;
  int dd = idx / DM, o = idx % DM;
  opwT[idx] = opw[o*DI + dd];
}

// -------- K5: merge + LayerNorm + SiLU(z) gate + out_proj. 16 positions/block.
__global__ void k_out(const float* __restrict__ ys, const float* __restrict__ z,
                      const float* __restrict__ lng, const float* __restrict__ lnb,
                      const float* __restrict__ opwT, float* __restrict__ out){
  __shared__ float yl[16][DI];
  __shared__ float red[16][3][2];
  __shared__ float part[16][DI];
  int t = threadIdx.x;             // 0..191
  int blk = blockIdx.x;            // b*256 + tile
  int b = blk >> 8;
  int s0 = (blk & 255) * 16;
  long base = (long)b*K_*L_*DI;
  int wid = t >> 6, lane = t & 63;
  float g = lng[t], bb = lnb[t];
  for (int p = 0; p < 16; p++){
    int s = s0 + p;
    int h = s >> 6, w = s & 63;
    int pos1 = (w<<6) | h;
    float y = ys[base + ((long)0*L_ + s)          *DI + t]
            + ys[base + ((long)1*L_ + pos1)       *DI + t]
            + ys[base + ((long)2*L_ + (L_-1-s))   *DI + t]
            + ys[base + ((long)3*L_ + (L_-1-pos1))*DI + t];
    yl[p][t] = y;
    float s1 = y, s2 = y*y;
    for (int off=32; off; off>>=1){
      s1 += __shfl_down(s1,off);
      s2 += __shfl_down(s2,off);
    }
    if (lane==0){ red[p][wid][0]=s1; red[p][wid][1]=s2; }
  }
  __syncthreads();
  const float* zp = z + ((long)b*L_ + s0)*DI;
  for (int p=0;p<16;p++){
    float sum = red[p][0][0]+red[p][1][0]+red[p][2][0];
    float sq  = red[p][0][1]+red[p][1][1]+red[p][2][1];
    float mu  = sum * (1.f/DI);
    float var = sq*(1.f/DI) - mu*mu;
    float rstd = rsqrtf(var + 1e-5f);
    float y = yl[p][t];
    float yn = (y-mu)*rstd*g + bb;
    float zv = zp[(long)p*DI + t];
    yl[p][t] = yn * (zv * sigmoidf_(zv));
  }
  __syncthreads();
  {
    int o = t % 96, half = t / 96;
    float acc[16];
    #pragma unroll
    for (int p=0;p<16;p++) acc[p]=0.f;
    for (int j4 = 0; j4 < 96; j4 += 4){
      int dd = half*96 + j4;
      float w0 = opwT[(dd+0)*DM + o];
      float w1 = opwT[(dd+1)*DM + o];
      float w2 = opwT[(dd+2)*DM + o];
      float w3 = opwT[(dd+3)*DM + o];
      #pragma unroll
      for (int p=0;p<16;p++){
        float4 yv = *(const float4*)&yl[p][dd];
        acc[p] += yv.x*w0 + yv.y*w1 + yv.z*w2 + yv.w*w3;
      }
    }
    #pragma unroll
    for (int p=0;p<16;p++) part[p][t] = acc[p];
  }
  __syncthreads();
  for (int i = t; i < 16*DM; i += 192){
    int p = i / DM, o2 = i % DM;
    out[((long)b*L_ + s0 + p)*DM + o2] = part[p][o2] + part[p][o2+96];
  }
}

extern "C" void kernel_launch(void* const* d_in, const int* in_sizes, int n_in,
                              void* d_out, int out_size, void* d_ws, size_t ws_size,
                              hipStream_t stream){
  const float* x    = (const float*)d_in[0];
  const float* ipw  = (const float*)d_in[1];
  const float* cw   = (const float*)d_in[2];
  const float* cb   = (const float*)d_in[3];
  const float* xpw  = (const float*)d_in[4];
  const float* dtw  = (const float*)d_in[5];
  const float* dtb  = (const float*)d_in[6];
  const float* Alog = (const float*)d_in[7];
  const float* Dvec = (const float*)d_in[8];
  const float* lng  = (const float*)d_in[9];
  const float* lnb  = (const float*)d_in[10];
  const float* opw  = (const float*)d_in[11];
  float* out = (float*)d_out;

  float* ws = (float*)d_ws;
  long szBDL  = (long)B_*L_*DI;         // 3,145,728
  long szBKDL = (long)B_*K_*L_*DI;      // 12,582,912
  long szBKNL = (long)B_*K_*L_*DS;      // 1,048,576
  float* xin   = ws;                    // dead after conv -> aprod/hstart overlay
  float* z     = xin + szBDL;
  float* xc    = z + szBDL;             // dead after scanC -> opwT overlay
  float* delta = xc + szBDL;
  float* Bsb   = delta + szBKDL;
  float* Csb   = Bsb + szBKNL;
  float* ysb   = Csb + szBKNL;
  float* aprod = xin;                   // 16*64*192*16 = 3,145,728 exact fit
  float* hend  = ysb;                   // head of ys; consumed before scanC writes
  float* opwT  = xc;                    // after scanC

  hipLaunchKernelGGL(k_inproj, dim3(B_*L_/TL), dim3(384), 0, stream, x, ipw, xin, z);
  hipLaunchKernelGGL(k_conv, dim3((int)(szBDL/256)), dim3(256), 0, stream, xin, cw, cb, xc);
  hipLaunchKernelGGL(k_proj, dim3(B_*K_*64), dim3(256), 0, stream, xc, xpw, dtw, dtb, delta, Bsb, Csb);
  hipLaunchKernelGGL(k_scanA, dim3(B_*K_*NC), dim3(192), 0, stream, xc, delta, Bsb, Alog, aprod, hend);
  hipLaunchKernelGGL(k_scanB, dim3(B_*K_*12), dim3(256), 0, stream, aprod, hend);
  hipLaunchKernelGGL(k_scanC, dim3(B_*K_*NC), dim3(192), 0, stream, xc, delta, Bsb, Csb, Alog, Dvec, aprod, ysb);
  hipLaunchKernelGGL(k_transpose, dim3(72), dim3(256), 0, stream, opw, opwT);
  hipLaunchKernelGGL(k_out, dim3(B_*256), dim3(192), 0, stream, ysb, z, lng, lnb, opwT, out);
}

// Round 4
// 424.841 us; speedup vs baseline: 4.8449x; 1.4253x over previous
//
#include <hip/hip_runtime.h>
#include <math.h>

#define B_ 4
#define H_ 64
#define W_ 64
#define L_ 4096
#define DM 96
#define DI 192
#define DS 16
#define RK 6
#define K_ 4
#define CPROJ 38   // RK + 2*DS
#define TL 8
#define NC 64      // chunks
#define CL 64      // chunk length

__device__ __forceinline__ float sigmoidf_(float x){ return 1.0f/(1.0f+expf(-x)); }
__device__ __forceinline__ float softplusf_(float x){ return (x>20.f)?x:log1pf(expf(x)); }

// inverse spatial map: scan position l for direction k at spatial position s
__device__ __forceinline__ int scan_pos(int k, int s){
  switch(k&3){
    case 0: return s;
    case 1: return ((s & 63) << 6) | (s >> 6);
    case 2: return L_-1-s;
    default: return L_-1-(((s & 63) << 6) | (s >> 6));
  }
}

// -------- K1: in_proj GEMM. xin (B,L,DI), z (B,L,DI)
__global__ void k_inproj(const float* __restrict__ x, const float* __restrict__ w,
                         float* __restrict__ xin, float* __restrict__ z){
  __shared__ float xs[TL][DM];
  int t = threadIdx.x;                     // 0..383
  long bl0 = (long)blockIdx.x * TL;
  for (int i = t; i < TL*DM; i += 384)
    xs[i/DM][i%DM] = x[bl0*DM + i];
  __syncthreads();
  float acc[TL];
  #pragma unroll
  for (int r=0;r<TL;r++) acc[r]=0.f;
  const float* wr = w + t*DM;
  for (int c=0;c<DM;c++){
    float wv = wr[c];
    #pragma unroll
    for (int r=0;r<TL;r++) acc[r] += wv * xs[r][c];
  }
  if (t < DI){
    for (int r=0;r<TL;r++)
      xin[(bl0 + r)*DI + t] = acc[r];
  } else {
    int e = t - DI;
    for (int r=0;r<TL;r++)
      z[(bl0 + r)*DI + e] = acc[r];
  }
}

// -------- K2: depthwise conv 3x3 + bias + SiLU. (B,L,DI) -> (B,L,DI)
__global__ void k_conv(const float* __restrict__ xin, const float* __restrict__ cw,
                       const float* __restrict__ cb, float* __restrict__ xc){
  long idx = (long)blockIdx.x*256 + threadIdx.x;
  if (idx >= (long)B_*L_*DI) return;
  int d = (int)(idx % DI);
  long bl = idx / DI;
  int l = (int)(bl % L_);
  long b = bl / L_;
  int h = l >> 6, w = l & 63;
  const float* wp = cw + d*9;
  const float* xp = xin + b*L_*DI + d;
  float acc = cb[d];
  #pragma unroll
  for (int di=0; di<3; di++){
    int hh = h + di - 1;
    if (hh < 0 || hh >= H_) continue;
    #pragma unroll
    for (int dj=0; dj<3; dj++){
      int ww = w + dj - 1;
      if (ww < 0 || ww >= W_) continue;
      acc += xp[(long)((hh<<6) + ww)*DI] * wp[di*3+dj];
    }
  }
  xc[idx] = acc * sigmoidf_(acc);
}

// -------- K3: x_proj + dt_proj + softplus. Gather-free staging; scatter on write.
// block = (b, k, 64-position spatial tile). delta (BK,L,DI), Bs/Cs (BK,L,DS)
__global__ void k_proj(const float* __restrict__ xc, const float* __restrict__ xpw,
                       const float* __restrict__ dtw, const float* __restrict__ dtb,
                       float* __restrict__ delta, float* __restrict__ Bsb, float* __restrict__ Csb){
  __shared__ float xt[DI][65];      // [d][li], pad -> conflict-free
  __shared__ float projRK[RK][65];  // dt-rank rows only
  int t = threadIdx.x;              // 0..255
  int blk = blockIdx.x;             // b*K*64 + k*64 + tile
  int tile = blk & 63;
  int k  = (blk >> 6) & 3;
  int b  = blk >> 8;
  int s0 = tile * 64;
  int bk = b*K_ + k;
  // coalesced stage: consecutive threads load consecutive d of row (s0+li)
  const float* xcb = xc + ((long)b*L_ + s0)*DI;
  for (int i = t; i < 64*DI; i += 256){
    int d = i % DI, li = i / DI;
    xt[d][li] = xcb[(long)li*DI + d];
  }
  __syncthreads();
  // GEMM: 640 units (li, cgrp), each thread computes c = cgrp+{0,10,20,30}
  const float* wb = xpw + (long)k*CPROJ*DI;
  for (int u = t; u < 640; u += 256){
    int li = u & 63;
    int cgrp = __builtin_amdgcn_readfirstlane(u >> 6);  // wave-uniform 0..9
    const float* w0 = wb + (cgrp     )*DI;
    const float* w1 = wb + (cgrp + 10)*DI;
    const float* w2 = wb + (cgrp + 20)*DI;
    const float* w3 = wb + (cgrp + 30 < CPROJ ? cgrp + 30 : 0)*DI;
    float a0=0.f, a1=0.f, a2=0.f, a3=0.f;
    #pragma unroll 4
    for (int dd = 0; dd < DI; dd++){
      float xv = xt[dd][li];
      a0 += xv * w0[dd];
      a1 += xv * w1[dd];
      a2 += xv * w2[dd];
      a3 += xv * w3[dd];
    }
    int s = s0 + li;
    int l = scan_pos(k, s);
    long rowBC = (long)bk*L_ + l;
    float av[4] = {a0,a1,a2,a3};
    #pragma unroll
    for (int j = 0; j < 4; j++){
      int c = cgrp + 10*j;
      if (c < RK) projRK[c][li] = av[j];
      else if (c < RK + DS) Bsb[rowBC*DS + (c-RK)] = av[j];
      else if (c < CPROJ)   Csb[rowBC*DS + (c-RK-DS)] = av[j];
    }
  }
  __syncthreads();
  // dt_proj + softplus, write (bk, l, d) rows (d-coalesced)
  for (int i = t; i < 64*DI; i += 256){
    int d = i % DI, li = i / DI;
    int l = scan_pos(k, s0 + li);
    const float* wr = dtw + (long)(k*DI + d)*RK;
    float acc = dtb[k*DI + d];
    #pragma unroll
    for (int r=0; r<RK; r++) acc += projRK[r][li]*wr[r];
    delta[((long)bk*L_ + l)*DI + d] = softplusf_(acc);
  }
}

__device__ __forceinline__ void scan_addr(int k, int chunk, int l0, int& sbase, int& sstep){
  switch(k){
    case 0: sbase = l0;            sstep = 1;   break;
    case 1: sbase = chunk;         sstep = 64;  break;
    case 2: sbase = L_-1-l0;       sstep = -1;  break;
    default: sbase = 4032 + 63 - chunk; sstep = -64; break;
  }
}

// -------- K4a: pass A. block=(bk,chunk), thread=d holds 16 n-states.
__global__ void k_scanA(const float* __restrict__ xc, const float* __restrict__ delta,
                        const float* __restrict__ Bsb, const float* __restrict__ Alog,
                        float* __restrict__ aprod, float* __restrict__ hend){
  __shared__ float Bt[CL][DS];
  int d = threadIdx.x;             // 0..191
  int blk = blockIdx.x;            // bk*NC + chunk
  int chunk = blk & (NC-1);
  int bk = blk >> 6;
  int k = bk & 3, b = bk >> 2;
  int l0 = chunk * CL;
  const float* Bg = Bsb + ((long)bk*L_ + l0)*DS;
  for (int i = d; i < CL*DS; i += 192) ((float*)Bt)[i] = Bg[i];
  float An2[DS], h[DS], ap[DS];
  const float* Ap = Alog + (k*DI + d)*DS;
  #pragma unroll
  for (int n=0;n<DS;n++){ An2[n] = -expf(Ap[n])*1.44269504f; h[n]=0.f; ap[n]=1.f; }
  __syncthreads();
  int sbase, sstep; scan_addr(k, chunk, l0, sbase, sstep);
  const float* dp = delta + ((long)bk*L_ + l0)*DI + d;
  const float* xp = xc + (long)b*L_*DI + d;
  for (int l=0; l<CL; l++){
    float dt = dp[(long)l*DI];
    float u  = xp[(long)(sbase + l*sstep)*DI];
    float dtu = dt*u;
    float bvf[DS];
    *(float4*)(bvf+0)  = *(const float4*)&Bt[l][0];
    *(float4*)(bvf+4)  = *(const float4*)&Bt[l][4];
    *(float4*)(bvf+8)  = *(const float4*)&Bt[l][8];
    *(float4*)(bvf+12) = *(const float4*)&Bt[l][12];
    #pragma unroll
    for (int n=0;n<DS;n++){
      float a = exp2f(dt*An2[n]);
      ap[n] *= a;
      h[n] = a*h[n] + dtu*bvf[n];
    }
  }
  long ob = ((long)blk*DI + d)*DS;
  #pragma unroll
  for (int q=0;q<4;q++){
    *(float4*)(aprod + ob + q*4) = make_float4(ap[q*4],ap[q*4+1],ap[q*4+2],ap[q*4+3]);
    *(float4*)(hend  + ob + q*4) = make_float4(h[q*4], h[q*4+1], h[q*4+2], h[q*4+3]);
  }
}

// -------- K4b: chunk-scan, register-batched. hstart written in-place to aprod.
__global__ void k_scanB(float* __restrict__ aprod, float* __restrict__ hend){
  int t = threadIdx.x;             // (dl,n) = 256
  int blk = blockIdx.x;            // bk*12 + p
  int p = blk % 12;
  int bk = blk / 12;
  long base = (long)bk*NC*DI*DS + p*256 + t;
  const long cstride = (long)DI*DS;   // 3072
  float hs = 0.f;
  for (int cb = 0; cb < NC; cb += 16){
    float a[16], e[16];
    #pragma unroll
    for (int j=0;j<16;j++){
      long idx = base + (long)(cb+j)*cstride;
      a[j] = aprod[idx];
      e[j] = hend[idx];
    }
    #pragma unroll
    for (int j=0;j<16;j++){
      long idx = base + (long)(cb+j)*cstride;
      aprod[idx] = hs;             // hstart for chunk cb+j
      hs = a[j]*hs + e[j];
    }
  }
}

// -------- K4c: pass C. seeded local scan, y = <h,C> + D*u. ys (BK,L,DI)
__global__ void k_scanC(const float* __restrict__ xc, const float* __restrict__ delta,
                        const float* __restrict__ Bsb, const float* __restrict__ Csb,
                        const float* __restrict__ Alog, const float* __restrict__ Dvec,
                        const float* __restrict__ hstart, float* __restrict__ ys){
  __shared__ float Bt[CL][DS];
  __shared__ float Ct[CL][DS];
  int d = threadIdx.x;
  int blk = blockIdx.x;
  int chunk = blk & (NC-1);
  int bk = blk >> 6;
  int k = bk & 3, b = bk >> 2;
  int l0 = chunk * CL;
  const float* Bg = Bsb + ((long)bk*L_ + l0)*DS;
  const float* Cg = Csb + ((long)bk*L_ + l0)*DS;
  for (int i = d; i < CL*DS; i += 192){ ((float*)Bt)[i] = Bg[i]; ((float*)Ct)[i] = Cg[i]; }
  float An2[DS], h[DS];
  const float* Ap = Alog + (k*DI + d)*DS;
  #pragma unroll
  for (int n=0;n<DS;n++) An2[n] = -expf(Ap[n])*1.44269504f;
  long hb = ((long)blk*DI + d)*DS;
  #pragma unroll
  for (int q=0;q<4;q++){
    float4 hv = *(const float4*)(hstart + hb + q*4);
    h[q*4]=hv.x; h[q*4+1]=hv.y; h[q*4+2]=hv.z; h[q*4+3]=hv.w;
  }
  float Dv = Dvec[k*DI + d];
  __syncthreads();
  int sbase, sstep; scan_addr(k, chunk, l0, sbase, sstep);
  const float* dp = delta + ((long)bk*L_ + l0)*DI + d;
  const float* xp = xc + (long)b*L_*DI + d;
  float* yp = ys + ((long)bk*L_ + l0)*DI + d;
  for (int l=0; l<CL; l++){
    float dt = dp[(long)l*DI];
    float u  = xp[(long)(sbase + l*sstep)*DI];
    float dtu = dt*u;
    float bvf[DS], cvf[DS];
    *(float4*)(bvf+0)  = *(const float4*)&Bt[l][0];
    *(float4*)(bvf+4)  = *(const float4*)&Bt[l][4];
    *(float4*)(bvf+8)  = *(const float4*)&Bt[l][8];
    *(float4*)(bvf+12) = *(const float4*)&Bt[l][12];
    *(float4*)(cvf+0)  = *(const float4*)&Ct[l][0];
    *(float4*)(cvf+4)  = *(const float4*)&Ct[l][4];
    *(float4*)(cvf+8)  = *(const float4*)&Ct[l][8];
    *(float4*)(cvf+12) = *(const float4*)&Ct[l][12];
    float y = 0.f;
    #pragma unroll
    for (int n=0;n<DS;n++){
      float a = exp2f(dt*An2[n]);
      h[n] = a*h[n] + dtu*bvf[n];
      y += h[n]*cvf[n];
    }
    yp[(long)l*DI] = y + Dv*u;
  }
}

// -------- transpose out_proj weight: opwT[dd][o] = opw[o][dd]
__global__ void k_transpose(const float* __restrict__ opw, float* __restrict__ opwT){
  int idx = blockIdx.x*256 + threadIdx.x;
  if (idx >= DM*DI) return;
  int dd = idx / DM, o = idx % DM;
  opwT[idx] = opw[o*DI + dd];
}

// -------- K5: merge + LayerNorm + SiLU(z) gate + out_proj. 16 positions/block.
__global__ void k_out(const float* __restrict__ ys, const float* __restrict__ z,
                      const float* __restrict__ lng, const float* __restrict__ lnb,
                      const float* __restrict__ opwT, float* __restrict__ out){
  __shared__ float yl[16][DI];
  __shared__ float red[16][3][2];
  __shared__ float part[16][DI];
  int t = threadIdx.x;             // 0..191
  int blk = blockIdx.x;            // b*256 + tile
  int b = blk >> 8;
  int s0 = (blk & 255) * 16;
  long base = (long)b*K_*L_*DI;
  int wid = t >> 6, lane = t & 63;
  float g = lng[t], bb = lnb[t];
  for (int p = 0; p < 16; p++){
    int s = s0 + p;
    int h = s >> 6, w = s & 63;
    int pos1 = (w<<6) | h;
    float y = ys[base + ((long)0*L_ + s)          *DI + t]
            + ys[base + ((long)1*L_ + pos1)       *DI + t]
            + ys[base + ((long)2*L_ + (L_-1-s))   *DI + t]
            + ys[base + ((long)3*L_ + (L_-1-pos1))*DI + t];
    yl[p][t] = y;
    float s1 = y, s2 = y*y;
    for (int off=32; off; off>>=1){
      s1 += __shfl_down(s1,off);
      s2 += __shfl_down(s2,off);
    }
    if (lane==0){ red[p][wid][0]=s1; red[p][wid][1]=s2; }
  }
  __syncthreads();
  const float* zp = z + ((long)b*L_ + s0)*DI;
  for (int p=0;p<16;p++){
    float sum = red[p][0][0]+red[p][1][0]+red[p][2][0];
    float sq  = red[p][0][1]+red[p][1][1]+red[p][2][1];
    float mu  = sum * (1.f/DI);
    float var = sq*(1.f/DI) - mu*mu;
    float rstd = rsqrtf(var + 1e-5f);
    float y = yl[p][t];
    float yn = (y-mu)*rstd*g + bb;
    float zv = zp[(long)p*DI + t];
    yl[p][t] = yn * (zv * sigmoidf_(zv));
  }
  __syncthreads();
  {
    int o = t % 96, half = t / 96;
    float acc[16];
    #pragma unroll
    for (int p=0;p<16;p++) acc[p]=0.f;
    for (int j4 = 0; j4 < 96; j4 += 4){
      int dd = half*96 + j4;
      float w0 = opwT[(dd+0)*DM + o];
      float w1 = opwT[(dd+1)*DM + o];
      float w2 = opwT[(dd+2)*DM + o];
      float w3 = opwT[(dd+3)*DM + o];
      #pragma unroll
      for (int p=0;p<16;p++){
        float4 yv = *(const float4*)&yl[p][dd];
        acc[p] += yv.x*w0 + yv.y*w1 + yv.z*w2 + yv.w*w3;
      }
    }
    #pragma unroll
    for (int p=0;p<16;p++) part[p][t] = acc[p];
  }
  __syncthreads();
  for (int i = t; i < 16*DM; i += 192){
    int p = i / DM, o2 = i % DM;
    out[((long)b*L_ + s0 + p)*DM + o2] = part[p][o2] + part[p][o2+96];
  }
}

extern "C" void kernel_launch(void* const* d_in, const int* in_sizes, int n_in,
                              void* d_out, int out_size, void* d_ws, size_t ws_size,
                              hipStream_t stream){
  const float* x    = (const float*)d_in[0];
  const float* ipw  = (const float*)d_in[1];
  const float* cw   = (const float*)d_in[2];
  const float* cb   = (const float*)d_in[3];
  const float* xpw  = (const float*)d_in[4];
  const float* dtw  = (const float*)d_in[5];
  const float* dtb  = (const float*)d_in[6];
  const float* Alog = (const float*)d_in[7];
  const float* Dvec = (const float*)d_in[8];
  const float* lng  = (const float*)d_in[9];
  const float* lnb  = (const float*)d_in[10];
  const float* opw  = (const float*)d_in[11];
  float* out = (float*)d_out;

  float* ws = (float*)d_ws;
  long szBDL  = (long)B_*L_*DI;         // 3,145,728
  long szBKDL = (long)B_*K_*L_*DI;      // 12,582,912
  long szBKNL = (long)B_*K_*L_*DS;      // 1,048,576
  float* xin   = ws;                    // dead after conv -> aprod/hstart overlay
  float* z     = xin + szBDL;
  float* xc    = z + szBDL;             // dead after scanC -> opwT overlay
  float* delta = xc + szBDL;
  float* Bsb   = delta + szBKDL;
  float* Csb   = Bsb + szBKNL;
  float* ysb   = Csb + szBKNL;
  float* aprod = xin;                   // 16*64*192*16 = 3,145,728 exact fit
  float* hend  = ysb;                   // head of ys; consumed before scanC writes
  float* opwT  = xc;                    // after scanC

  hipLaunchKernelGGL(k_inproj, dim3(B_*L_/TL), dim3(384), 0, stream, x, ipw, xin, z);
  hipLaunchKernelGGL(k_conv, dim3((int)(szBDL/256)), dim3(256), 0, stream, xin, cw, cb, xc);
  hipLaunchKernelGGL(k_proj, dim3(B_*K_*64), dim3(256), 0, stream, xc, xpw, dtw, dtb, delta, Bsb, Csb);
  hipLaunchKernelGGL(k_scanA, dim3(B_*K_*NC), dim3(192), 0, stream, xc, delta, Bsb, Alog, aprod, hend);
  hipLaunchKernelGGL(k_scanB, dim3(B_*K_*12), dim3(256), 0, stream, aprod, hend);
  hipLaunchKernelGGL(k_scanC, dim3(B_*K_*NC), dim3(192), 0, stream, xc, delta, Bsb, Csb, Alog, Dvec, aprod, ysb);
  hipLaunchKernelGGL(k_transpose, dim3(72), dim3(256), 0, stream, opw, opwT);
  hipLaunchKernelGGL(k_out, dim3(B_*256), dim3(192), 0, stream, ysb, z, lng, lnb, opwT, out);
}